// Round 1
// baseline (62.833 us; speedup 1.0000x reference)
//
#include <hip/hip_runtime.h>

#define G_GEN 65
#define FEAT 8192   // 32*16*16
#define NBASE (G_GEN * FEAT)

// Kernel 1: per-feature stats. f-th thread reads x[g*FEAT + f] for g=0..64
// (coalesced across threads for each g), computes center/radius -> scale, val, cross.
__global__ void feat_stats(const float* __restrict__ x,
                           const float* __restrict__ lambdas,
                           float* __restrict__ ws_scale,
                           float* __restrict__ ws_val,
                           int* __restrict__ ws_cross) {
    int f = blockIdx.x * blockDim.x + threadIdx.x;
    if (f >= FEAT) return;
    float c = x[f];                 // generator 0 = center
    float r = 0.f;
    #pragma unroll 8
    for (int g = 1; g < G_GEN; ++g) r += fabsf(x[g * FEAT + f]);
    float l = c - r;
    float u = c + r;
    bool zero_m = (u <= 0.f);
    bool cross  = (!zero_m) && (l < 0.f);
    float d     = u - l;
    float denom = (d > 0.f) ? d : 1.f;
    float slope = u / denom;
    float lam   = lambdas[f];
    float val   = (lam >= slope) ? (-l * lam * 0.5f) : (u * (1.f - lam) * 0.5f);
    val = cross ? val : 0.f;
    float scale = zero_m ? 0.f : (cross ? lam : 1.f);
    ws_scale[f] = scale;
    ws_val[f]   = val;
    ws_cross[f] = cross ? 1 : 0;
}

// Kernel 2: single-block prefix scan of cross flags (global cumsum order),
// then scatter val[f] into eps block at row (G_GEN + rank[f]), col f.
__global__ void scan_scatter(const float* __restrict__ ws_val,
                             const int* __restrict__ ws_cross,
                             float* __restrict__ out) {
    __shared__ int sums[256];
    const int t = threadIdx.x;
    const int PER = FEAT / 256;           // 32 features per thread, contiguous
    const int base = t * PER;
    int flags[PER];
    int local = 0;
    #pragma unroll
    for (int i = 0; i < PER; ++i) { flags[i] = ws_cross[base + i]; local += flags[i]; }
    sums[t] = local;
    __syncthreads();
    // Hillis-Steele inclusive scan over 256 thread-sums
    for (int off = 1; off < 256; off <<= 1) {
        int v   = sums[t];
        int add = (t >= off) ? sums[t - off] : 0;
        __syncthreads();
        sums[t] = v + add;
        __syncthreads();
    }
    int rank = (t > 0) ? sums[t - 1] : 0;  // exclusive prefix for this thread's chunk
    #pragma unroll
    for (int i = 0; i < PER; ++i) {
        if (flags[i]) {
            out[(size_t)(G_GEN + rank) * FEAT + (base + i)] = ws_val[base + i];
            ++rank;
        }
    }
}

// Kernel 3: base block out[g*FEAT+f] = x[g*FEAT+f]*scale[f] + (g==0)*val[f]
__global__ void write_base(const float* __restrict__ x,
                           const float* __restrict__ ws_scale,
                           const float* __restrict__ ws_val,
                           float* __restrict__ out) {
    int idx = blockIdx.x * blockDim.x + threadIdx.x;
    if (idx >= NBASE) return;
    int f = idx & (FEAT - 1);
    float v = x[idx] * ws_scale[f];
    if (idx < FEAT) v += ws_val[f];    // g == 0 row gets +val
    out[idx] = v;
}

extern "C" void kernel_launch(void* const* d_in, const int* in_sizes, int n_in,
                              void* d_out, int out_size, void* d_ws, size_t ws_size,
                              hipStream_t stream) {
    const float* x       = (const float*)d_in[0];
    const float* lambdas = (const float*)d_in[1];
    float* out = (float*)d_out;

    float* ws_scale = (float*)d_ws;
    float* ws_val   = ws_scale + FEAT;
    int*   ws_cross = (int*)(ws_val + FEAT);

    // Zero the eps block region (rows G_GEN .. G_GEN+FEAT): 256 MiB memset node.
    hipMemsetAsync((char*)d_out + (size_t)G_GEN * FEAT * sizeof(float), 0,
                   (size_t)FEAT * FEAT * sizeof(float), stream);

    feat_stats<<<FEAT / 256, 256, 0, stream>>>(x, lambdas, ws_scale, ws_val, ws_cross);
    scan_scatter<<<1, 256, 0, stream>>>(ws_val, ws_cross, out);
    write_base<<<(NBASE + 255) / 256, 256, 0, stream>>>(x, ws_scale, ws_val, out);
}